// Round 1
// baseline (435.777 us; speedup 1.0000x reference)
//
#include <hip/hip_runtime.h>

#define HH_EPS 1e-6f

// ---------------------------------------------------------------------------
// K1: one block. Compute Gram matrix G = V V^T (136 pairs, wave-parallel),
// beta_k = 2/(G[k][k]+eps), then the WY "T" factor (16x16 lower-triangular):
//   T[k][k] = beta_k ;  T[k][j<k] = -beta_k * sum_{i=j..k-1} G[k][i]*T[i][j]
// Write T (256 floats) to ws[0..256).
// ---------------------------------------------------------------------------
__global__ __launch_bounds__(256) void hh_setup_T(const float* __restrict__ V,
                                                  float* __restrict__ ws) {
    __shared__ float G[16][16];
    __shared__ float T[16][16];
    const int t = threadIdx.x;
    const int wave = t >> 6;
    const int lane = t & 63;
    const float4* V4 = (const float4*)V;

    int cnt = 0;
    for (int k = 0; k < 16; ++k) {
        for (int i = 0; i <= k; ++i, ++cnt) {
            if ((cnt & 3) != wave) continue;   // wave-uniform branch
            float acc = 0.f;
            #pragma unroll
            for (int c = 0; c < 16; ++c) {
                float4 a = V4[k * 1024 + lane + 64 * c];
                float4 b = V4[i * 1024 + lane + 64 * c];
                acc = fmaf(a.x, b.x, acc);
                acc = fmaf(a.y, b.y, acc);
                acc = fmaf(a.z, b.z, acc);
                acc = fmaf(a.w, b.w, acc);
            }
            #pragma unroll
            for (int off = 32; off >= 1; off >>= 1)
                acc += __shfl_xor(acc, off, 64);
            if (lane == 0) { G[k][i] = acc; G[i][k] = acc; }
        }
    }
    __syncthreads();

    if (t == 0) {
        float beta[16];
        #pragma unroll
        for (int k = 0; k < 16; ++k) beta[k] = 2.0f / (G[k][k] + HH_EPS);
        for (int k = 0; k < 16; ++k) {
            for (int j = 0; j < k; ++j) {
                float s = 0.f;
                for (int i = j; i < k; ++i) s = fmaf(G[k][i], T[i][j], s);
                T[k][j] = -beta[k] * s;
            }
            T[k][k] = beta[k];
            for (int j = k + 1; j < 16; ++j) T[k][j] = 0.f;
        }
    }
    __syncthreads();
    ws[t] = T[t >> 4][t & 15];
}

// ---------------------------------------------------------------------------
// K2: Bt = T * V  (16 x 4096), row-major, written to ws[256 .. 256+65536).
// 64 blocks x 256 threads; each thread produces one float4 of Bt.
// ---------------------------------------------------------------------------
__global__ __launch_bounds__(256) void hh_compute_B(const float* __restrict__ V,
                                                    float* __restrict__ ws) {
    const float* T = ws;
    float4* B4 = (float4*)(ws + 256);
    const float4* V4 = (const float4*)V;
    const int tid = blockIdx.x * 256 + threadIdx.x;  // 0..16383
    const int j = tid >> 10;                          // vector row 0..15
    const int d4 = tid & 1023;                        // float4 column
    float4 acc = make_float4(0.f, 0.f, 0.f, 0.f);
    for (int k = 0; k <= j; ++k) {                    // T lower-triangular
        const float tv = T[j * 16 + k];
        const float4 v = V4[k * 1024 + d4];
        acc.x = fmaf(tv, v.x, acc.x);
        acc.y = fmaf(tv, v.y, acc.y);
        acc.z = fmaf(tv, v.z, acc.z);
        acc.w = fmaf(tv, v.w, acc.w);
    }
    B4[tid] = acc;
}

// ---------------------------------------------------------------------------
// K3: fused apply. 4 rows per block; rows live in registers (16 float4/thr).
//   w[j][r] = row_r . Bt[j]    (16 independent dots vs the ORIGINAL row)
//   out_r   = row_r - sum_j w[j][r] * V[j]
// Single batched reduction phase: per-j wave reduce -> LDS -> 64-thread
// cross-wave sum -> broadcast. Only 2 __syncthreads total.
// ---------------------------------------------------------------------------
__global__ __launch_bounds__(256, 4) void hh_apply(const float* __restrict__ X,
                                                   const float* __restrict__ V,
                                                   const float* __restrict__ ws,
                                                   float* __restrict__ Out) {
    const float4* X4 = (const float4*)X;
    const float4* V4 = (const float4*)V;
    const float4* B4 = (const float4*)(ws + 256);
    float4* O4 = (float4*)Out;

    const int t = threadIdx.x;
    const int wave = t >> 6;
    const int lane = t & 63;
    const int rb = blockIdx.x * 4;  // first of 4 rows (8192 rows total)

    // Load 4 rows, coalesced: thread t owns float4 columns {t, t+256, t+512, t+768}
    float4 xr[4][4];
    #pragma unroll
    for (int r = 0; r < 4; ++r)
        #pragma unroll
        for (int c = 0; c < 4; ++c)
            xr[r][c] = X4[(rb + r) * 1024 + t + 256 * c];

    __shared__ float pw[16][4][4];  // [j][wave][row]
    __shared__ float wf[16][4];     // [j][row]

    // Phase 1: 16 dots per row against Bt rows
    for (int j = 0; j < 16; ++j) {
        float p0 = 0.f, p1 = 0.f, p2 = 0.f, p3 = 0.f;
        #pragma unroll
        for (int c = 0; c < 4; ++c) {
            const float4 b = B4[j * 1024 + t + 256 * c];
            p0 = fmaf(xr[0][c].x, b.x, p0); p0 = fmaf(xr[0][c].y, b.y, p0);
            p0 = fmaf(xr[0][c].z, b.z, p0); p0 = fmaf(xr[0][c].w, b.w, p0);
            p1 = fmaf(xr[1][c].x, b.x, p1); p1 = fmaf(xr[1][c].y, b.y, p1);
            p1 = fmaf(xr[1][c].z, b.z, p1); p1 = fmaf(xr[1][c].w, b.w, p1);
            p2 = fmaf(xr[2][c].x, b.x, p2); p2 = fmaf(xr[2][c].y, b.y, p2);
            p2 = fmaf(xr[2][c].z, b.z, p2); p2 = fmaf(xr[2][c].w, b.w, p2);
            p3 = fmaf(xr[3][c].x, b.x, p3); p3 = fmaf(xr[3][c].y, b.y, p3);
            p3 = fmaf(xr[3][c].z, b.z, p3); p3 = fmaf(xr[3][c].w, b.w, p3);
        }
        #pragma unroll
        for (int off = 32; off >= 1; off >>= 1) {
            p0 += __shfl_xor(p0, off, 64);
            p1 += __shfl_xor(p1, off, 64);
            p2 += __shfl_xor(p2, off, 64);
            p3 += __shfl_xor(p3, off, 64);
        }
        if (lane == 0) {
            pw[j][wave][0] = p0; pw[j][wave][1] = p1;
            pw[j][wave][2] = p2; pw[j][wave][3] = p3;
        }
    }
    __syncthreads();
    if (t < 64) {
        const int j = t >> 2, r = t & 3;
        wf[j][r] = pw[j][0][r] + pw[j][1][r] + pw[j][2][r] + pw[j][3][r];
    }
    __syncthreads();

    // Phase 2: out_r = row_r - sum_j wf[j][r] * V[j]
    for (int j = 0; j < 16; ++j) {
        const float w0 = -wf[j][0], w1 = -wf[j][1];
        const float w2 = -wf[j][2], w3 = -wf[j][3];
        #pragma unroll
        for (int c = 0; c < 4; ++c) {
            const float4 v = V4[j * 1024 + t + 256 * c];
            xr[0][c].x = fmaf(w0, v.x, xr[0][c].x);
            xr[0][c].y = fmaf(w0, v.y, xr[0][c].y);
            xr[0][c].z = fmaf(w0, v.z, xr[0][c].z);
            xr[0][c].w = fmaf(w0, v.w, xr[0][c].w);
            xr[1][c].x = fmaf(w1, v.x, xr[1][c].x);
            xr[1][c].y = fmaf(w1, v.y, xr[1][c].y);
            xr[1][c].z = fmaf(w1, v.z, xr[1][c].z);
            xr[1][c].w = fmaf(w1, v.w, xr[1][c].w);
            xr[2][c].x = fmaf(w2, v.x, xr[2][c].x);
            xr[2][c].y = fmaf(w2, v.y, xr[2][c].y);
            xr[2][c].z = fmaf(w2, v.z, xr[2][c].z);
            xr[2][c].w = fmaf(w2, v.w, xr[2][c].w);
            xr[3][c].x = fmaf(w3, v.x, xr[3][c].x);
            xr[3][c].y = fmaf(w3, v.y, xr[3][c].y);
            xr[3][c].z = fmaf(w3, v.z, xr[3][c].z);
            xr[3][c].w = fmaf(w3, v.w, xr[3][c].w);
        }
    }

    #pragma unroll
    for (int r = 0; r < 4; ++r)
        #pragma unroll
        for (int c = 0; c < 4; ++c)
            O4[(rb + r) * 1024 + t + 256 * c] = xr[r][c];
}

// ---------------------------------------------------------------------------
extern "C" void kernel_launch(void* const* d_in, const int* in_sizes, int n_in,
                              void* d_out, int out_size, void* d_ws, size_t ws_size,
                              hipStream_t stream) {
    const float* X = (const float*)d_in[0];   // (4,2048,4096) f32 = 8192 rows
    const float* V = (const float*)d_in[1];   // (16,4096) f32
    float* O = (float*)d_out;
    float* ws = (float*)d_ws;                 // needs 256+65536 floats = 257 KiB

    hh_setup_T<<<1, 256, 0, stream>>>(V, ws);
    hh_compute_B<<<64, 256, 0, stream>>>(V, ws);
    hh_apply<<<2048, 256, 0, stream>>>(X, V, ws, O);
}

// Round 2
// 290.806 us; speedup vs baseline: 1.4985x; 1.4985x over previous
//
#include <hip/hip_runtime.h>

#define HH_EPS 1e-6f

// ws layout (floats): [0..256) = G (16x16), [256..512) = T (16x16 row-major)

// ---------------------------------------------------------------------------
// K1: Gram matrix. 136 blocks, one per pair (k,i) i<=k. Block-wide dot of
// V[k] . V[i] over 4096 elems; thread t handles float4 cols {t, t+256, ...}.
// ---------------------------------------------------------------------------
__global__ __launch_bounds__(256) void hh_gram(const float* __restrict__ V,
                                               float* __restrict__ ws) {
    // map blockIdx.x -> (k, i), i <= k, 136 pairs
    int b = blockIdx.x;
    int k = 0;
    while (b >= k + 1) { b -= k + 1; ++k; }
    const int i = b;

    const float4* V4 = (const float4*)V;
    const int t = threadIdx.x;
    const int wave = t >> 6;
    const int lane = t & 63;

    float acc = 0.f;
    #pragma unroll
    for (int c = 0; c < 4; ++c) {
        const float4 a = V4[k * 1024 + t + 256 * c];
        const float4 v = V4[i * 1024 + t + 256 * c];
        acc = fmaf(a.x, v.x, acc);
        acc = fmaf(a.y, v.y, acc);
        acc = fmaf(a.z, v.z, acc);
        acc = fmaf(a.w, v.w, acc);
    }
    #pragma unroll
    for (int off = 32; off >= 1; off >>= 1)
        acc += __shfl_xor(acc, off, 64);

    __shared__ float red[4];
    if (lane == 0) red[wave] = acc;
    __syncthreads();
    if (t == 0) {
        const float g = red[0] + red[1] + red[2] + red[3];
        ws[k * 16 + i] = g;
        ws[i * 16 + k] = g;
    }
}

// ---------------------------------------------------------------------------
// K2: T factor. One wave; lane j owns column T[.][j] in registers.
//   T[k][k] = beta_k ;  T[k][j<k] = -beta_k * sum_{i=j..k-1} G[k][i]*T[i][j]
// Fully unrolled (compile-time indices only), predicated on i>=j.
// ---------------------------------------------------------------------------
__global__ __launch_bounds__(64) void hh_T(float* __restrict__ ws) {
    __shared__ float Gs[256];
    const int t = threadIdx.x;
    #pragma unroll
    for (int q = 0; q < 4; ++q) Gs[t * 4 + q] = ws[t * 4 + q];
    __syncthreads();

    const int j = t;            // only lanes 0..15 produce columns
    float tc[16];
    #pragma unroll
    for (int k = 0; k < 16; ++k) {
        const float beta = 2.0f / (Gs[k * 16 + k] + HH_EPS);
        float s = 0.f;
        #pragma unroll
        for (int i = 0; i < k; ++i) {
            const float g = Gs[k * 16 + i];
            s = fmaf((i >= j) ? g : 0.f, tc[i], s);
        }
        tc[k] = (j == k) ? beta : ((j < k) ? (-beta * s) : 0.f);
    }
    if (j < 16) {
        #pragma unroll
        for (int i = 0; i < 16; ++i) ws[256 + i * 16 + j] = tc[i];
    }
}

// ---------------------------------------------------------------------------
// K3: fused apply. 4 rows/block, rows in registers (16 float4/thread).
//   y[j][r] = row_r . V[j]          (16 independent dots vs ORIGINAL rows)
//   w       = T . y                  (tiny, in-LDS)
//   out_r   = row_r - sum_j w[j][r] * V[j]
// ---------------------------------------------------------------------------
__global__ __launch_bounds__(256, 4) void hh_apply(const float* __restrict__ X,
                                                   const float* __restrict__ V,
                                                   const float* __restrict__ ws,
                                                   float* __restrict__ Out) {
    const float4* X4 = (const float4*)X;
    const float4* V4 = (const float4*)V;
    float4* O4 = (float4*)Out;

    const int t = threadIdx.x;
    const int wave = t >> 6;
    const int lane = t & 63;
    const int rb = blockIdx.x * 4;

    __shared__ float Ts[256];       // T row-major
    __shared__ float pw[16][4][4];  // [j][wave][row] partials
    __shared__ float yf[16][4];     // y[j][row]
    __shared__ float wf[16][4];     // w[k][row]

    // Load 4 rows (coalesced) + T
    float4 xr[4][4];
    #pragma unroll
    for (int r = 0; r < 4; ++r)
        #pragma unroll
        for (int c = 0; c < 4; ++c)
            xr[r][c] = X4[(rb + r) * 1024 + t + 256 * c];
    Ts[t] = ws[256 + t];

    // Phase 1: 16 dots per row against V rows
    for (int j = 0; j < 16; ++j) {
        float p0 = 0.f, p1 = 0.f, p2 = 0.f, p3 = 0.f;
        #pragma unroll
        for (int c = 0; c < 4; ++c) {
            const float4 b = V4[j * 1024 + t + 256 * c];
            p0 = fmaf(xr[0][c].x, b.x, p0); p0 = fmaf(xr[0][c].y, b.y, p0);
            p0 = fmaf(xr[0][c].z, b.z, p0); p0 = fmaf(xr[0][c].w, b.w, p0);
            p1 = fmaf(xr[1][c].x, b.x, p1); p1 = fmaf(xr[1][c].y, b.y, p1);
            p1 = fmaf(xr[1][c].z, b.z, p1); p1 = fmaf(xr[1][c].w, b.w, p1);
            p2 = fmaf(xr[2][c].x, b.x, p2); p2 = fmaf(xr[2][c].y, b.y, p2);
            p2 = fmaf(xr[2][c].z, b.z, p2); p2 = fmaf(xr[2][c].w, b.w, p2);
            p3 = fmaf(xr[3][c].x, b.x, p3); p3 = fmaf(xr[3][c].y, b.y, p3);
            p3 = fmaf(xr[3][c].z, b.z, p3); p3 = fmaf(xr[3][c].w, b.w, p3);
        }
        #pragma unroll
        for (int off = 32; off >= 1; off >>= 1) {
            p0 += __shfl_xor(p0, off, 64);
            p1 += __shfl_xor(p1, off, 64);
            p2 += __shfl_xor(p2, off, 64);
            p3 += __shfl_xor(p3, off, 64);
        }
        if (lane == 0) {
            pw[j][wave][0] = p0; pw[j][wave][1] = p1;
            pw[j][wave][2] = p2; pw[j][wave][3] = p3;
        }
    }
    __syncthreads();

    // y[j][r] = sum over waves
    if (t < 64) {
        const int j = t >> 2, r = t & 3;
        yf[j][r] = pw[j][0][r] + pw[j][1][r] + pw[j][2][r] + pw[j][3][r];
    }
    __syncthreads();

    // w = T . y  (16x16 matvec per row)
    if (t < 64) {
        const int k = t >> 2, r = t & 3;
        float s = 0.f;
        #pragma unroll
        for (int j = 0; j < 16; ++j) s = fmaf(Ts[k * 16 + j], yf[j][r], s);
        wf[k][r] = s;
    }
    __syncthreads();

    // Phase 2: out_r = row_r - sum_j w[j][r] * V[j]
    for (int j = 0; j < 16; ++j) {
        const float w0 = -wf[j][0], w1 = -wf[j][1];
        const float w2 = -wf[j][2], w3 = -wf[j][3];
        #pragma unroll
        for (int c = 0; c < 4; ++c) {
            const float4 v = V4[j * 1024 + t + 256 * c];
            xr[0][c].x = fmaf(w0, v.x, xr[0][c].x);
            xr[0][c].y = fmaf(w0, v.y, xr[0][c].y);
            xr[0][c].z = fmaf(w0, v.z, xr[0][c].z);
            xr[0][c].w = fmaf(w0, v.w, xr[0][c].w);
            xr[1][c].x = fmaf(w1, v.x, xr[1][c].x);
            xr[1][c].y = fmaf(w1, v.y, xr[1][c].y);
            xr[1][c].z = fmaf(w1, v.z, xr[1][c].z);
            xr[1][c].w = fmaf(w1, v.w, xr[1][c].w);
            xr[2][c].x = fmaf(w2, v.x, xr[2][c].x);
            xr[2][c].y = fmaf(w2, v.y, xr[2][c].y);
            xr[2][c].z = fmaf(w2, v.z, xr[2][c].z);
            xr[2][c].w = fmaf(w2, v.w, xr[2][c].w);
            xr[3][c].x = fmaf(w3, v.x, xr[3][c].x);
            xr[3][c].y = fmaf(w3, v.y, xr[3][c].y);
            xr[3][c].z = fmaf(w3, v.z, xr[3][c].z);
            xr[3][c].w = fmaf(w3, v.w, xr[3][c].w);
        }
    }

    #pragma unroll
    for (int r = 0; r < 4; ++r)
        #pragma unroll
        for (int c = 0; c < 4; ++c)
            O4[(rb + r) * 1024 + t + 256 * c] = xr[r][c];
}

// ---------------------------------------------------------------------------
extern "C" void kernel_launch(void* const* d_in, const int* in_sizes, int n_in,
                              void* d_out, int out_size, void* d_ws, size_t ws_size,
                              hipStream_t stream) {
    const float* X = (const float*)d_in[0];   // (4,2048,4096) f32 = 8192 rows
    const float* V = (const float*)d_in[1];   // (16,4096) f32
    float* O = (float*)d_out;
    float* ws = (float*)d_ws;                 // needs 512 floats

    hh_gram<<<136, 256, 0, stream>>>(V, ws);
    hh_T<<<1, 64, 0, stream>>>(ws);
    hh_apply<<<2048, 256, 0, stream>>>(X, V, ws, O);
}